// Round 8
// baseline (177.424 us; speedup 1.0000x reference)
//
#include <hip/hip_runtime.h>

#define ROWS 8192
#define COLS 8192
#define BR 128
#define BC 128
#define NBC (COLS / BC)              // 64 block-cols
#define NBLOCKS ((ROWS / BR) * NBC)  // 4096 blocks

typedef float f32x4 __attribute__((ext_vector_type(4)));

// ---------------- Kernel A: pure-read block min/max reduction ----------------
// One 256-thread workgroup per 128x128 block; writes {scale, zp} per block.
__global__ __launch_bounds__(256) void reduce_blocks(
    const float* __restrict__ in,
    float2* __restrict__ params) {

    const int bidx = blockIdx.x;
    const int brow = bidx / NBC;
    const int bcol = bidx % NBC;
    const int t = threadIdx.x;

    const float* base = in + (size_t)(brow * BR) * COLS + (size_t)(bcol * BC);

    const int rofs = t >> 5;        // 0..7
    const int c4   = (t & 31) * 4;  // 0..124

    float vmin = INFINITY;
    float vmax = -INFINITY;
    #pragma unroll
    for (int i = 0; i < 16; ++i) {
        const f32x4 v = *reinterpret_cast<const f32x4*>(
            base + (size_t)(i * 8 + rofs) * COLS + c4);
        vmin = fminf(vmin, fminf(fminf(v.x, v.y), fminf(v.z, v.w)));
        vmax = fmaxf(vmax, fmaxf(fmaxf(v.x, v.y), fmaxf(v.z, v.w)));
    }

    #pragma unroll
    for (int o = 32; o > 0; o >>= 1) {
        vmin = fminf(vmin, __shfl_xor(vmin, o));
        vmax = fmaxf(vmax, __shfl_xor(vmax, o));
    }

    __shared__ float smin[4], smax[4];
    const int wave = t >> 6;
    if ((t & 63) == 0) { smin[wave] = vmin; smax[wave] = vmax; }
    __syncthreads();

    if (t == 0) {
        const float bmin = fminf(fminf(smin[0], smin[1]), fminf(smin[2], smin[3]));
        const float bmax = fmaxf(fmaxf(smax[0], smax[1]), fmaxf(smax[2], smax[3]));
        const float rng = bmax - bmin;
        float scale, zp;
        if (rng == 0.0f) {
            scale = 1.0f;
            zp = 0.0f;
        } else {
            scale = rng / 255.0f;                            // exact fp32 div, matches jax
            zp = (float)(int)rintf(-128.0f - bmin / scale);  // nearest-even = jnp.round
        }
        params[bidx] = make_float2(scale, zp);
    }
}

// ---------------- Kernel B: pure-stream replicated write ----------------
// Linear grid-stride over the output; params table is L2-resident (32 KB).
#define FILL_WGS 2048
#define FILL_THREADS (FILL_WGS * 256)             // 524288
#define N4_PER_ARRAY ((size_t)ROWS * COLS / 4)    // 16777216 float4
#define FILL_ITERS (N4_PER_ARRAY / FILL_THREADS)  // 32

__global__ __launch_bounds__(256) void fill_out(
    const float2* __restrict__ params,
    float* __restrict__ scale_out,
    float* __restrict__ zp_out) {

    const int tid = blockIdx.x * 256 + threadIdx.x;  // 0..524287

    #pragma unroll 4
    for (int it = 0; it < (int)FILL_ITERS; ++it) {
        const size_t i4   = (size_t)it * FILL_THREADS + (size_t)tid;
        const size_t elem = i4 * 4;
        const int row = (int)(elem >> 13);      // /COLS
        const int col = (int)(elem & (COLS - 1));
        const int bid = ((row >> 7) << 6) | (col >> 7);
        const float2 p = params[bid];
        const f32x4 sv = {p.x, p.x, p.x, p.x};
        const f32x4 zv = {p.y, p.y, p.y, p.y};
        *reinterpret_cast<f32x4*>(scale_out + elem) = sv;
        *reinterpret_cast<f32x4*>(zp_out + elem) = zv;
    }
}

extern "C" void kernel_launch(void* const* d_in, const int* in_sizes, int n_in,
                              void* d_out, int out_size, void* d_ws, size_t ws_size,
                              hipStream_t stream) {
    const float* in = (const float*)d_in[0];
    float* out = (float*)d_out;
    float* scale_out = out;
    float* zp_out = out + (size_t)ROWS * COLS;
    float2* params = (float2*)d_ws;  // 4096 * 8 B = 32 KB

    reduce_blocks<<<dim3(NBLOCKS), dim3(256), 0, stream>>>(in, params);
    fill_out<<<dim3(FILL_WGS), dim3(256), 0, stream>>>(params, scale_out, zp_out);
}

// Round 9
// 134.642 us; speedup vs baseline: 1.3177x; 1.3177x over previous
//
#include <hip/hip_runtime.h>

#define ROWS 8192
#define COLS 8192
#define BR 128
#define BC 128
#define NBC (COLS / BC)   // 64 blocks per row of blocks

typedef float f32x4 __attribute__((ext_vector_type(4)));

// Fused: one 256-thread workgroup per 128x128 block.
// Phase 1: block min/max reduction (NT loads). Phase 2: broadcast write (NT stores).
__global__ __launch_bounds__(256) void observer_block_qparams(
    const float* __restrict__ in,
    float* __restrict__ scale_out,
    float* __restrict__ zp_out) {

    const int bidx = blockIdx.x;
    const int brow = bidx / NBC;
    const int bcol = bidx % NBC;
    const int t = threadIdx.x;

    const size_t block_base = (size_t)(brow * BR) * COLS + (size_t)(bcol * BC);
    const float* base = in + block_base;

    // Each sweep: 256 threads x 4 floats = 1024 floats = 8 rows of 128.
    const int rofs = t >> 5;          // 0..7 (row within 8-row sweep)
    const int c4   = (t & 31) * 4;    // 0..124 (col, float4-aligned)

    float vmin = INFINITY;
    float vmax = -INFINITY;
    #pragma unroll
    for (int i = 0; i < 16; ++i) {
        const f32x4 v = __builtin_nontemporal_load(
            reinterpret_cast<const f32x4*>(base + (size_t)(i * 8 + rofs) * COLS + c4));
        vmin = fminf(vmin, fminf(fminf(v.x, v.y), fminf(v.z, v.w)));
        vmax = fmaxf(vmax, fmaxf(fmaxf(v.x, v.y), fmaxf(v.z, v.w)));
    }

    // 64-lane wave butterfly reduce
    #pragma unroll
    for (int o = 32; o > 0; o >>= 1) {
        vmin = fminf(vmin, __shfl_xor(vmin, o));
        vmax = fmaxf(vmax, __shfl_xor(vmax, o));
    }

    __shared__ float smin[4], smax[4];
    __shared__ float s_scale, s_zp;
    const int wave = t >> 6;
    if ((t & 63) == 0) { smin[wave] = vmin; smax[wave] = vmax; }
    __syncthreads();

    if (t == 0) {
        const float bmin = fminf(fminf(smin[0], smin[1]), fminf(smin[2], smin[3]));
        const float bmax = fmaxf(fmaxf(smax[0], smax[1]), fmaxf(smax[2], smax[3]));
        const float rng = bmax - bmin;
        float scale, zp;
        if (rng == 0.0f) {
            scale = 1.0f;
            zp = 0.0f;
        } else {
            scale = rng / 255.0f;                            // exact fp32 div, matches jax
            zp = (float)(int)rintf(-128.0f - bmin / scale);  // nearest-even = jnp.round
        }
        s_scale = scale;
        s_zp = zp;
    }
    __syncthreads();

    const float sc = s_scale;
    const float z  = s_zp;
    const f32x4 sv = {sc, sc, sc, sc};
    const f32x4 zv = {z, z, z, z};

    float* so = scale_out + block_base;
    float* zo = zp_out + block_base;
    #pragma unroll
    for (int i = 0; i < 16; ++i) {
        const size_t off = (size_t)(i * 8 + rofs) * COLS + c4;
        __builtin_nontemporal_store(sv, reinterpret_cast<f32x4*>(so + off));
        __builtin_nontemporal_store(zv, reinterpret_cast<f32x4*>(zo + off));
    }
}

extern "C" void kernel_launch(void* const* d_in, const int* in_sizes, int n_in,
                              void* d_out, int out_size, void* d_ws, size_t ws_size,
                              hipStream_t stream) {
    const float* in = (const float*)d_in[0];
    float* out = (float*)d_out;
    float* scale_out = out;
    float* zp_out = out + (size_t)ROWS * COLS;

    observer_block_qparams<<<dim3((ROWS / BR) * NBC), dim3(256), 0, stream>>>(
        in, scale_out, zp_out);
}